// Round 6
// baseline (38.644 us; speedup 1.0000x reference)
//
#include <hip/hip_runtime.h>
#include <math.h>

#define TOPK 10
#define G 8              // stage-1 blocks per batch
#define CHUNK 1050       // N / G
#define NT 256
#define S1_PER 5         // ceil(CHUNK / NT)
#define FILLB 2048       // fill-only blocks

// ---------- helpers ----------

// Order-preserving f32 -> u32 (monotone: a<b  =>  enc(a)<enc(b)).
__device__ __forceinline__ unsigned int f32_ordkey(float f) {
    unsigned int u = __float_as_uint(f);
    return (u & 0x80000000u) ? ~u : (u | 0x80000000u);
}

__device__ __forceinline__ unsigned long long wave_max_u64(unsigned long long k) {
    #pragma unroll
    for (int off = 32; off > 0; off >>= 1) {
        unsigned long long o = __shfl_xor(k, off, 64);
        k = (o > k) ? o : k;
    }
    return k;
}

__device__ __forceinline__ unsigned long long wave_min_u64(unsigned long long k) {
    #pragma unroll
    for (int off = 32; off > 0; off >>= 1) {
        unsigned long long o = __shfl_xor(k, off, 64);
        k = (o < k) ? o : k;
    }
    return k;
}

__device__ __forceinline__ float iou_box(float4 bx, float g0, float g1, float g2,
                                         float g3, float area_g) {
    const float ix1 = fmaxf(bx.x, g0), iy1 = fmaxf(bx.y, g1);
    const float ix2 = fminf(bx.z, g2), iy2 = fminf(bx.w, g3);
    const float inter  = fmaxf(ix2 - ix1, 0.0f) * fmaxf(iy2 - iy1, 0.0f);
    const float area_p = (bx.z - bx.x) * (bx.w - bx.y);
    return fmaxf(inter / (area_p + area_g - inter), 1e-9f);
}

// ---------- fused kernel: role-split ----------
// grid = BG + FILLB blocks x 256.
//   blocks [0, BG):        stage-1 ONLY for (b,g) — exit early, no fill share.
//   blocks [BG, BG+FILLB): zero-fill ONLY, grid-stride over FILLB blocks.
// Dispatch order puts stage1 first, so fill blocks backfill CU slots as
// stage1 retires; fill stays write-BW-bound the whole time and stage1 hides.
__global__ __launch_bounds__(NT) void taa_fused(
    const float* __restrict__ scores,   // B,N,C
    const float* __restrict__ boxes,    // B,N,4
    const float* __restrict__ anchors,  // N,2
    const int*   __restrict__ labels,   // B
    const float* __restrict__ gts,      // B,1,4
    float4* __restrict__ out4, size_t n4,
    unsigned long long* __restrict__ cand,  // [B][G*4*TOPK] = [B][320]
    unsigned long long* __restrict__ dkw,   // [B][G*4]      = [B][32]
    int* __restrict__ anyf,                 // [B][G*4]
    int BG, int N, int C)
{
    const int tid = threadIdx.x;

    if (blockIdx.x < (unsigned)BG) {
        const int b    = blockIdx.x / G;
        const int g    = blockIdx.x % G;
        const int lane = tid & 63;
        const int wave = tid >> 6;      // 0..3
        const int base = g * CHUNK;

        const float g0 = gts[b*4+0], g1 = gts[b*4+1], g2 = gts[b*4+2], g3 = gts[b*4+3];
        const int   cls = labels[b];
        const float gcx = (g0 + g2) * 0.5f, gcy = (g1 + g3) * 0.5f;
        const float area_g = (g2 - g0) * (g3 - g1);

        unsigned long long key[S1_PER];
        unsigned long long dkey = ~0ull;
        int anyin = 0;

        #pragma unroll
        for (int j = 0; j < S1_PER; ++j) {
            const int ii = tid + j * NT;
            const int i  = base + ii;
            if (ii < CHUNK) {
                const float2 a = ((const float2*)anchors)[i];
                const bool in = (a.x >= g0) && (a.x <= g2) && (a.y >= g1) && (a.y <= g3);
                anyin |= (int)in;

                const float dx = a.x - gcx, dy = a.y - gcy;
                const float d2 = dx*dx + dy*dy;
                const unsigned long long dk =
                    ((unsigned long long)__float_as_uint(d2) << 32) | (unsigned int)i;
                dkey = dk < dkey ? dk : dkey;   // ties -> lower idx (low bits)

                float m = -1.0f;
                if (in) {   // lazy: boxes/scores touched only for in-box anchors (~3%)
                    const float4 bx = ((const float4*)boxes)[(size_t)b * N + i];
                    const float iou = iou_box(bx, g0, g1, g2, g3, area_g);
                    const float sc = scores[((size_t)b * N + i) * C + cls];
                    const float cs = 1.0f / (1.0f + expf(-sc));
                    const float i2 = iou * iou;
                    m = sqrtf(cs) * (i2 * i2 * i2);
                }
                key[j] = ((unsigned long long)f32_ordkey(m) << 32) | (unsigned int)(~(unsigned int)i);
            } else {
                key[j] = 0ull;          // below any real key (key(-1.0) > 0)
            }
        }

        // Wave top-10 by iterative max + zero-out (keys unique: idx in low bits).
        unsigned long long* wc = cand + ((size_t)b * (G*4*TOPK)) + (g*4 + wave) * TOPK;
        for (int r = 0; r < TOPK; ++r) {
            unsigned long long lm = key[0];
            #pragma unroll
            for (int j = 1; j < S1_PER; ++j) lm = key[j] > lm ? key[j] : lm;
            const unsigned long long w = wave_max_u64(lm);
            #pragma unroll
            for (int j = 0; j < S1_PER; ++j) if (key[j] == w) key[j] = 0ull;
            if (lane == 0) wc[r] = w;
        }

        // Wave any(is_in) + min-d2 key.
        const int wany = __any(anyin);
        const unsigned long long wdk = wave_min_u64(dkey);
        if (lane == 0) {
            anyf[b * (G*4) + g*4 + wave] = wany;
            dkw [b * (G*4) + g*4 + wave] = wdk;
        }
        return;   // stage-1 blocks take no fill share
    }

    // Fill-only blocks.
    const size_t fb     = blockIdx.x - (unsigned)BG;
    const size_t stride = (size_t)FILLB * NT;
    const float4 z = make_float4(0.f, 0.f, 0.f, 0.f);
    for (size_t i = fb * NT + tid; i < n4; i += stride)
        out4[i] = z;
}

// ---------- stage 2: merge + scatter ----------
// grid = B blocks x 64 threads.
__global__ __launch_bounds__(64) void taa_stage2(
    const float* __restrict__ boxes,    // B,N,4
    const int*   __restrict__ labels,   // B
    const float* __restrict__ gts,      // B,1,4
    const unsigned long long* __restrict__ cand,
    const unsigned long long* __restrict__ dkw,
    const int* __restrict__ anyf,
    float* __restrict__ tb, float* __restrict__ ts, float* __restrict__ fg,
    int N, int C)
{
    const int b    = blockIdx.x;
    const int lane = threadIdx.x;

    const float g0 = gts[b*4+0], g1 = gts[b*4+1], g2 = gts[b*4+2], g3 = gts[b*4+3];
    const bool  gt_valid = (g2 > g0) && (g3 > g1);
    const int   cls = labels[b];
    const float area_g = (g2 - g0) * (g3 - g1);

    const int a = __any((lane < 32) ? anyf[b*32 + lane] : 0);

    int wi = -1;          // winner anchor index for this lane (if any)
    if (a) {
        unsigned long long k[5];
        #pragma unroll
        for (int j = 0; j < 5; ++j) k[j] = cand[(size_t)b * 320 + j*64 + lane];

        unsigned long long mywin = 0ull;
        for (int r = 0; r < TOPK; ++r) {
            unsigned long long lm = k[0];
            #pragma unroll
            for (int j = 1; j < 5; ++j) lm = k[j] > lm ? k[j] : lm;
            const unsigned long long w = wave_max_u64(lm);
            #pragma unroll
            for (int j = 0; j < 5; ++j) if (k[j] == w) k[j] = 0ull;
            if (lane == r) mywin = w;
        }
        // sel <=> metric >= +0.0 <=> top bit set (only in-box anchors qualify).
        if (lane < TOPK && (mywin & 0x8000000000000000ull))
            wi = (int)(~(unsigned int)(mywin & 0xffffffffu));
    } else {
        // Fallback: single winner = global argmin-d2 (metric > 0 always).
        unsigned long long dk = (lane < 32) ? dkw[b*32 + lane] : ~0ull;
        const unsigned long long m = wave_min_u64(dk);
        if (lane == 0) wi = (int)(m & 0xffffffffu);
    }

    if (gt_valid && wi >= 0) {
        const float4 bx = ((const float4*)boxes)[(size_t)b * N + wi];
        const float iou = iou_box(bx, g0, g1, g2, g3, area_g);
        fg[(size_t)b * N + wi] = 1.0f;
        ((float4*)tb)[(size_t)b * N + wi] = make_float4(g0, g1, g2, g3);
        ts[((size_t)b * N + wi) * C + cls] = iou;
    }
}

extern "C" void kernel_launch(void* const* d_in, const int* in_sizes, int n_in,
                              void* d_out, int out_size, void* d_ws, size_t ws_size,
                              hipStream_t stream) {
    const float* scores  = (const float*)d_in[0];
    const float* boxes   = (const float*)d_in[1];
    const float* anchors = (const float*)d_in[2];
    const int*   labels  = (const int*)d_in[3];
    const float* gts     = (const float*)d_in[4];

    const int B = in_sizes[3];
    const int N = in_sizes[2] / 2;
    const int C = in_sizes[0] / (B * N);
    const int BG = B * G;

    float* tb = (float*)d_out;
    float* ts = tb + (size_t)B * N * 4;
    float* fg = ts + (size_t)B * N * C;

    // Workspace layout (8B-aligned).
    unsigned long long* cand = (unsigned long long*)d_ws;                 // B*320*8
    unsigned long long* dkw  = cand + (size_t)B * 320;                    // B*32*8
    int*                anyf = (int*)(dkw + (size_t)B * 32);              // B*32*4

    const size_t n4 = ((size_t)out_size * sizeof(float)) / sizeof(float4);

    taa_fused<<<BG + FILLB, NT, 0, stream>>>(scores, boxes, anchors, labels, gts,
                                             (float4*)d_out, n4, cand, dkw, anyf,
                                             BG, N, C);

    taa_stage2<<<B, 64, 0, stream>>>(boxes, labels, gts, cand, dkw, anyf,
                                     tb, ts, fg, N, C);
}